// Round 9
// baseline (276.431 us; speedup 1.0000x reference)
//
#include <hip/hip_runtime.h>
#include <math.h>

#define BSZ    8192
#define DDIM   256
#define SCALE  33.33333333333333f   // 1/0.03
#define C_OFF  34.0f                // fixed LSE offset: |sim*SCALE| <= 33.34
#define SC_L2E 48.08983470f         // SCALE * log2(e)
#define C2     49.05163139f         // C_OFF * log2(e)
#define LN2    0.6931471805599453f

typedef __bf16 bf16_t;
typedef __bf16 bf16x8 __attribute__((ext_vector_type(8)));
typedef float  floatx4 __attribute__((ext_vector_type(4)));

__device__ __forceinline__ bf16x8 cvt8(const float* __restrict__ g)
{
    const float4 lo = *(const float4*)g;
    const float4 hi = *(const float4*)(g + 4);
    bf16x8 v;
    v[0] = (bf16_t)lo.x; v[1] = (bf16_t)lo.y; v[2] = (bf16_t)lo.z; v[3] = (bf16_t)lo.w;
    v[4] = (bf16_t)hi.x; v[5] = (bf16_t)hi.y; v[6] = (bf16_t)hi.z; v[7] = (bf16_t)hi.w;
    return v;
}

// ---------------------------------------------------------------- prep
// Plain row-major fp32->bf16 for both tensors (no permute — B is read direct
// from global now, LDS banks irrelevant). blocks<16 zero s_row/s_col;
// block 0 zeroes possum/cnt.
__global__ __launch_bounds__(256) void prep_kernel(
    const float* __restrict__ za, const float* __restrict__ zt,
    bf16_t* __restrict__ za_bf, bf16_t* __restrict__ zt_bf,
    float* __restrict__ zbase)
{
    const int bid = blockIdx.x, tid = threadIdx.x;
    if (bid < 1024) {
        const int i = (bid * 256 + tid) * 8;
        *(bf16x8*)&za_bf[i] = cvt8(za + i);
        if (bid < 16) {
            const int z = bid * 1024 + tid * 4;
            *(float4*)&zbase[z] = (float4){0.f, 0.f, 0.f, 0.f};
            if (bid == 0 && tid == 0) {
                zbase[16384] = 0.f;          // possum
                ((int*)zbase)[16385] = 0;    // cnt
            }
        }
    } else {
        const int i = ((bid - 1024) * 256 + tid) * 8;
        *(bf16x8*)&zt_bf[i] = cvt8(zt + i);
    }
}

// ---------------------------------------------------------------- sim + merged finalize
// BARRIER-FREE K-loop: B fragments loaded straight from global (zt_bf) into
// registers — no LDS staging, no __syncthreads in the K-loop, so the compiler
// can hoist loads across MFMA with fine-grained vmcnt (the m97-barrier-drain
// stall is structurally gone). 4-wave reuse of B served by L1/L2.
// A resident in VGPRs (R6-proven). Epilogue/diag/reductions = R6-proven code.
__global__ __launch_bounds__(256, 2) void sim_fused(
    const bf16_t* __restrict__ za_bf, const bf16_t* __restrict__ zt_bf,
    const int* __restrict__ pid,
    float* __restrict__ s_row, float* __restrict__ s_col,
    float* __restrict__ possum, int* __restrict__ cnt,
    float* __restrict__ out)
{
    __shared__ int   pidc[512];
    __shared__ float colsum[512];
    __shared__ float lsw[4];
    __shared__ int   difw[4];
    __shared__ int   lastflag;

    const int bid   = blockIdx.x;
    const int strip = bid & 15, band = bid >> 4;
    const int row0  = band * 128, scol0 = strip * 512;
    const int tid   = threadIdx.x, lane = tid & 63, wid = tid >> 6;
    const int q     = lane >> 4, lc = lane & 15;
    const int rbase = row0 + wid * 32;

    pidc[tid]         = pid[scol0 + tid];
    pidc[tid + 256]   = pid[scol0 + tid + 256];
    colsum[tid]       = 0.f;
    colsum[tid + 256] = 0.f;

    // A resident: af[m][kc] = A[rbase+m*16+lc][kc*32 + q*8 ..+8]
    bf16x8 af[2][8];
    #pragma unroll
    for (int m = 0; m < 2; m++) {
        const bf16_t* ga = za_bf + (size_t)(rbase + m * 16 + lc) * DDIM + q * 8;
        #pragma unroll
        for (int kc = 0; kc < 8; kc++)
            af[m][kc] = *(const bf16x8*)(ga + kc * 32);
    }

    int prw[2][4];
    #pragma unroll
    for (int m = 0; m < 2; m++)
        #pragma unroll
        for (int r = 0; r < 4; r++)
            prw[m][r] = pid[rbase + m * 16 + q * 4 + r];

    __syncthreads();   // pidc ready (the only pre-epilogue barrier)

    float rowp[8] = {0.f, 0.f, 0.f, 0.f, 0.f, 0.f, 0.f, 0.f};
    float dsum = 0.f;
    const int diag_t = (row0 - scol0) >> 7;   // tile holding the diagonal if in [0,4)

    for (int t = 0; t < 4; t++) {
        floatx4 acc[2][8];
        #pragma unroll
        for (int m = 0; m < 2; m++)
            #pragma unroll
            for (int n = 0; n < 8; n++)
                acc[m][n] = (floatx4){0.f, 0.f, 0.f, 0.f};

        // per-lane B base: row (scol0 + t*128 + n*16 + lc), k offset q*8
        const bf16_t* Bt = zt_bf + (size_t)(scol0 + t * 128 + lc) * DDIM + q * 8;

        #pragma unroll
        for (int kc = 0; kc < 8; kc++) {
            bf16x8 bfr[8];
            #pragma unroll
            for (int n = 0; n < 8; n++)
                bfr[n] = *(const bf16x8*)(Bt + (size_t)(n * 16) * DDIM + kc * 32);
            #pragma unroll
            for (int m = 0; m < 2; m++)
                #pragma unroll
                for (int n = 0; n < 8; n++)
                    acc[m][n] = __builtin_amdgcn_mfma_f32_16x16x32_bf16(
                        af[m][kc], bfr[n], acc[m][n], 0, 0, 0);
        }

        // ---------- epilogue for tile t
        int pc[8];
        #pragma unroll
        for (int n = 0; n < 8; n++) pc[n] = pidc[t * 128 + n * 16 + lc];

        float colp[8] = {0.f, 0.f, 0.f, 0.f, 0.f, 0.f, 0.f, 0.f};
        #pragma unroll
        for (int m = 0; m < 2; m++) {
            #pragma unroll
            for (int r = 0; r < 4; r++) {
                const int pr = prw[m][r];
                float rsum = 0.f;
                #pragma unroll
                for (int n = 0; n < 8; n++) {
                    float e = __builtin_amdgcn_exp2f(fmaf(acc[m][n][r], SC_L2E, -C2));
                    e = (pr != pc[n]) ? e : 0.f;
                    rsum += e;
                    colp[n] += e;
                }
                rowp[m * 4 + r] += rsum;
            }
        }

        if (t == diag_t) {   // diagonal fixup — constant-index select chains only
            #pragma unroll      // (R5 lesson: dynamic reg-array indexing = scratch)
            for (int m = 0; m < 2; m++) {
                const int nstar = wid * 2 + m;
                #pragma unroll
                for (int r = 0; r < 4; r++) {
                    float v = 0.f;
                    #pragma unroll
                    for (int n = 0; n < 8; n++)
                        v = (n == nstar) ? acc[m][n][r] : v;
                    float e = __builtin_amdgcn_exp2f(fmaf(v, SC_L2E, -C2));
                    const bool own = (lc == q * 4 + r);
                    e = own ? e : 0.f;
                    rowp[m * 4 + r] += e;
                    #pragma unroll
                    for (int n = 0; n < 8; n++)
                        colp[n] += (n == nstar) ? e : 0.f;
                    dsum += own ? v * SCALE : 0.f;
                }
            }
        }

        #pragma unroll
        for (int n = 0; n < 8; n++) {
            colp[n] += __shfl_xor(colp[n], 16, 64);
            colp[n] += __shfl_xor(colp[n], 32, 64);
        }
        if (q == 0) {
            #pragma unroll
            for (int n = 0; n < 8; n++)
                atomicAdd(&colsum[t * 128 + n * 16 + lc], colp[n]);
        }
    }

    // ---------- row sums
    #pragma unroll
    for (int i = 0; i < 8; i++) {
        rowp[i] += __shfl_xor(rowp[i], 1, 64);
        rowp[i] += __shfl_xor(rowp[i], 2, 64);
        rowp[i] += __shfl_xor(rowp[i], 4, 64);
        rowp[i] += __shfl_xor(rowp[i], 8, 64);
    }
    float rw = rowp[0];
    #pragma unroll
    for (int idx = 1; idx < 8; idx++)
        rw = (lc == idx) ? rowp[idx] : rw;
    if (lc < 8)
        atomicAdd(&s_row[rbase + (lc >> 2) * 16 + q * 4 + (lc & 3)], rw);

    // ---------- Σpos (diag blocks only)
    if ((unsigned)diag_t < 4u) {
        #pragma unroll
        for (int b = 1; b <= 32; b <<= 1) dsum += __shfl_xor(dsum, b, 64);
        if (lane == 0) atomicAdd(possum, dsum);
    }

    // ---------- col sums flush
    __syncthreads();
    atomicAdd(&s_col[scol0 + tid], colsum[tid]);
    atomicAdd(&s_col[scol0 + tid + 256], colsum[tid + 256]);

    // ---------- merged finalize (last block via device-scope counter)
    __threadfence();
    __syncthreads();
    if (tid == 0) lastflag = (atomicAdd(cnt, 1) == (int)gridDim.x - 1);
    __syncthreads();
    if (lastflag) {
        __threadfence();
        float ls = 0.f;        // Σ ln over s_row||s_col (contiguous 16384 floats)
        for (int j = tid; j < 16384; j += 256)
            ls += __builtin_amdgcn_logf(atomicAdd(&s_row[j], 0.f));
        ls *= LN2;
        int dif = 0;
        const int p0 = pid[0];
        for (int j = tid; j < 8192; j += 256) dif |= (pid[j] != p0);
        #pragma unroll
        for (int b = 1; b <= 32; b <<= 1) {
            ls  += __shfl_xor(ls, b, 64);
            dif |= __shfl_xor(dif, b, 64);
        }
        if (lane == 0) { lsw[wid] = ls; difw[wid] = dif; }
        __syncthreads();
        if (tid == 0) {
            float T = lsw[0] + lsw[1] + lsw[2] + lsw[3];
            const int F = difw[0] | difw[1] | difw[2] | difw[3];
            const float ps = atomicAdd(possum, 0.0f);
            T += 2.0f * (float)BSZ * C_OFF - 2.0f * ps;
            out[0] = F ? T / (2.0f * (float)BSZ) : 0.0f;
        }
    }
}

// ---------------------------------------------------------------- launcher
extern "C" void kernel_launch(void* const* d_in, const int* in_sizes, int n_in,
                              void* d_out, int out_size, void* d_ws, size_t ws_size,
                              hipStream_t stream)
{
    const float* za  = (const float*)d_in[0];
    const float* zt  = (const float*)d_in[1];
    const int*   pid = (const int*)d_in[2];
    float* out = (float*)d_out;

    // ws: za_bf 4MB | zt_bf 4MB | s_row[8192] s_col[8192] possum cnt
    bf16_t* za_bf = (bf16_t*)d_ws;
    bf16_t* zt_bf = za_bf + (size_t)BSZ * DDIM;
    float*  s_row = (float*)(zt_bf + (size_t)BSZ * DDIM);
    float*  s_col = s_row + BSZ;
    float*  possum = s_col + BSZ;
    int*    cnt    = (int*)(possum + 1);

    prep_kernel<<<dim3(2048), 256, 0, stream>>>(za, zt, za_bf, zt_bf, s_row);

    sim_fused<<<dim3(1024), 256, 0, stream>>>(za_bf, zt_bf, pid,
                                              s_row, s_col, possum, cnt, out);
}

// Round 10
// 201.538 us; speedup vs baseline: 1.3716x; 1.3716x over previous
//
#include <hip/hip_runtime.h>
#include <math.h>

#define BSZ    8192
#define DDIM   256
#define SCALE  33.33333333333333f   // 1/0.03
#define C_OFF  34.0f                // fixed LSE offset: |sim*SCALE| <= 33.34
#define SC_L2E 48.08983470f         // SCALE * log2(e)
#define C2     49.05163139f         // C_OFF * log2(e)
#define LN2    0.6931471805599453f

typedef __bf16 bf16_t;
typedef __bf16 bf16x8 __attribute__((ext_vector_type(8)));
typedef float  floatx4 __attribute__((ext_vector_type(4)));

__device__ __forceinline__ bf16x8 cvt8(const float* __restrict__ g)
{
    const float4 lo = *(const float4*)g;
    const float4 hi = *(const float4*)(g + 4);
    bf16x8 v;
    v[0] = (bf16_t)lo.x; v[1] = (bf16_t)lo.y; v[2] = (bf16_t)lo.z; v[3] = (bf16_t)lo.w;
    v[4] = (bf16_t)hi.x; v[5] = (bf16_t)hi.y; v[6] = (bf16_t)hi.z; v[7] = (bf16_t)hi.w;
    return v;
}

// ---------------------------------------------------------------- prep (R6-identical)
// blocks [0,1024): za -> za_bf (row layout) + zero reduction ws (first 16 blocks)
// blocks [1024,2048): zt -> zt_perm, chunk-ordered: 8KB chunk = (colblock cb, kc);
//   slot P holds col cb*128+(P>>2), k = kc*32 + ((P&3)^(((P>>2)>>1)&3))*8
__global__ __launch_bounds__(256) void prep_kernel(
    const float* __restrict__ za, const float* __restrict__ zt,
    bf16_t* __restrict__ za_bf, bf16_t* __restrict__ zt_perm,
    float* __restrict__ zbase)
{
    const int bid = blockIdx.x, tid = threadIdx.x;
    if (bid < 1024) {
        const int i = (bid * 256 + tid) * 8;
        *(bf16x8*)&za_bf[i] = cvt8(za + i);
        if (bid < 16) {
            const int z = bid * 1024 + tid * 4;
            *(float4*)&zbase[z] = (float4){0.f, 0.f, 0.f, 0.f};
            if (bid == 0 && tid == 0) {
                zbase[16384] = 0.f;          // possum
                ((int*)zbase)[16385] = 0;    // cnt
            }
        }
    } else {
        const int S     = (bid - 1024) * 256 + tid;   // global 16B-slot id
        const int chunk = S >> 9, P = S & 511;
        const int col   = P >> 2, sp = P & 3;
        const int sl    = sp ^ ((col >> 1) & 3);
        const int cb    = chunk >> 3, kc = chunk & 7;
        const float* src = zt + (size_t)(cb * 128 + col) * DDIM + kc * 32 + sl * 8;
        *(bf16x8*)(zt_perm + (size_t)S * 8) = cvt8(src);
    }
}

// ---------------------------------------------------------------- sim (R6 core) + merged finalize
// R6-proven: grid 64 bands x 16 strips, 4 waves, A resident from za_bf,
// B staged via fire-and-forget global_load_lds (1KB/issue, dbuf 2x8KB,
// 1 barrier/32-k chunk), zero bank conflicts, launch_bounds(256,2) VGPR~112.
// Deltas (individually proven R7-R9): Σpos scalar, last-block finalize.
__global__ __launch_bounds__(256, 2) void sim_fused(
    const bf16_t* __restrict__ za_bf, const bf16_t* __restrict__ zt_perm,
    const int* __restrict__ pid,
    float* __restrict__ s_row, float* __restrict__ s_col,
    float* __restrict__ possum, int* __restrict__ cnt,
    float* __restrict__ out)
{
    __shared__ __align__(16) bf16_t Bs[2][128 * 32];   // 2 x 8 KB
    __shared__ int   pidc[512];
    __shared__ float colsum[512];
    __shared__ float lsw[4];
    __shared__ int   difw[4];
    __shared__ int   lastflag;

    const int bid   = blockIdx.x;
    const int strip = bid & 15, band = bid >> 4;
    const int row0  = band * 128, scol0 = strip * 512;
    const int tid   = threadIdx.x, lane = tid & 63, wid = tid >> 6;
    const int q     = lane >> 4, lc = lane & 15;
    const int rbase = row0 + wid * 32;

    pidc[tid]         = pid[scol0 + tid];
    pidc[tid + 256]   = pid[scol0 + tid + 256];
    colsum[tid]       = 0.f;
    colsum[tid + 256] = 0.f;

    // A fragments resident: af[m][kc] = A[rbase+m*16+lc][kc*32 + q*8 ..+8]
    bf16x8 af[2][8];
    #pragma unroll
    for (int m = 0; m < 2; m++) {
        const bf16_t* ga = za_bf + (size_t)(rbase + m * 16 + lc) * DDIM + q * 8;
        #pragma unroll
        for (int kc = 0; kc < 8; kc++)
            af[m][kc] = *(const bf16x8*)(ga + kc * 32);
    }

    int prw[2][4];
    #pragma unroll
    for (int m = 0; m < 2; m++)
        #pragma unroll
        for (int r = 0; r < 4; r++)
            prw[m][r] = pid[rbase + m * 16 + q * 4 + r];

    const char* zp = (const char*)zt_perm + (size_t)(strip * 32) * 8192
                   + (wid * 64 + lane) * 16;

#define STAGE(g, b)                                                              \
    do {                                                                         \
        const char* _s = zp + (size_t)(g) * 8192;                                \
        char* _d = (char*)Bs[b] + wid * 1024;                                    \
        __builtin_amdgcn_global_load_lds(                                        \
            (const __attribute__((address_space(1))) void*)_s,                   \
            (__attribute__((address_space(3))) void*)_d, 16, 0, 0);              \
        __builtin_amdgcn_global_load_lds(                                        \
            (const __attribute__((address_space(1))) void*)(_s + 4096),          \
            (__attribute__((address_space(3))) void*)(_d + 4096), 16, 0, 0);     \
    } while (0)

    STAGE(0, 0);   // prologue

    float rowp[8] = {0.f, 0.f, 0.f, 0.f, 0.f, 0.f, 0.f, 0.f};
    float dsum = 0.f;
    const int diag_t = (row0 - scol0) >> 7;   // tile holding the diagonal if in [0,4)
    const int xoff   = (lc >> 1) & 3;

    for (int t = 0; t < 4; t++) {
        floatx4 acc[2][8];
        #pragma unroll
        for (int m = 0; m < 2; m++)
            #pragma unroll
            for (int n = 0; n < 8; n++)
                acc[m][n] = (floatx4){0.f, 0.f, 0.f, 0.f};

        #pragma unroll
        for (int kc = 0; kc < 8; kc++) {
            __syncthreads();                 // chunk g landed (vmcnt drain at barrier)
            const int g = t * 8 + kc;
            if (g + 1 < 32) STAGE(g + 1, (g + 1) & 1);   // fire-and-forget prefetch

            const char* B = (const char*)Bs[g & 1];
            bf16x8 bfr[8];
            #pragma unroll
            for (int n = 0; n < 8; n++)
                bfr[n] = *(const bf16x8*)(B + (n * 16 + lc) * 64 + ((q ^ xoff) * 16));

            #pragma unroll
            for (int m = 0; m < 2; m++)
                #pragma unroll
                for (int n = 0; n < 8; n++)
                    acc[m][n] = __builtin_amdgcn_mfma_f32_16x16x32_bf16(
                        af[m][kc], bfr[n], acc[m][n], 0, 0, 0);
        }

        // ---------- epilogue for tile t (next chunk's prefetch in flight)
        int pc[8];
        #pragma unroll
        for (int n = 0; n < 8; n++) pc[n] = pidc[t * 128 + n * 16 + lc];

        float colp[8] = {0.f, 0.f, 0.f, 0.f, 0.f, 0.f, 0.f, 0.f};
        #pragma unroll
        for (int m = 0; m < 2; m++) {
            #pragma unroll
            for (int r = 0; r < 4; r++) {
                const int pr = prw[m][r];
                float rsum = 0.f;
                #pragma unroll
                for (int n = 0; n < 8; n++) {
                    float e = __builtin_amdgcn_exp2f(fmaf(acc[m][n][r], SC_L2E, -C2));
                    e = (pr != pc[n]) ? e : 0.f;
                    rsum += e;
                    colp[n] += e;
                }
                rowp[m * 4 + r] += rsum;
            }
        }

        if (t == diag_t) {   // diagonal fixup — constant-index select chains only
            #pragma unroll      // (R5 lesson: dynamic reg-array indexing = scratch)
            for (int m = 0; m < 2; m++) {
                const int nstar = wid * 2 + m;
                #pragma unroll
                for (int r = 0; r < 4; r++) {
                    float v = 0.f;
                    #pragma unroll
                    for (int n = 0; n < 8; n++)
                        v = (n == nstar) ? acc[m][n][r] : v;
                    float e = __builtin_amdgcn_exp2f(fmaf(v, SC_L2E, -C2));
                    const bool own = (lc == q * 4 + r);
                    e = own ? e : 0.f;
                    rowp[m * 4 + r] += e;
                    #pragma unroll
                    for (int n = 0; n < 8; n++)
                        colp[n] += (n == nstar) ? e : 0.f;
                    dsum += own ? v * SCALE : 0.f;   // Σpos contribution
                }
            }
        }

        #pragma unroll
        for (int n = 0; n < 8; n++) {
            colp[n] += __shfl_xor(colp[n], 16, 64);
            colp[n] += __shfl_xor(colp[n], 32, 64);
        }
        if (q == 0) {
            #pragma unroll
            for (int n = 0; n < 8; n++)
                atomicAdd(&colsum[t * 128 + n * 16 + lc], colp[n]);
        }
    }

    // ---------- row sums
    #pragma unroll
    for (int i = 0; i < 8; i++) {
        rowp[i] += __shfl_xor(rowp[i], 1, 64);
        rowp[i] += __shfl_xor(rowp[i], 2, 64);
        rowp[i] += __shfl_xor(rowp[i], 4, 64);
        rowp[i] += __shfl_xor(rowp[i], 8, 64);
    }
    float rw = rowp[0];
    #pragma unroll
    for (int idx = 1; idx < 8; idx++)
        rw = (lc == idx) ? rowp[idx] : rw;
    if (lc < 8)
        atomicAdd(&s_row[rbase + (lc >> 2) * 16 + q * 4 + (lc & 3)], rw);

    // ---------- Σpos (diag blocks only: 256 atomics total)
    if ((unsigned)diag_t < 4u) {
        #pragma unroll
        for (int b = 1; b <= 32; b <<= 1) dsum += __shfl_xor(dsum, b, 64);
        if (lane == 0) atomicAdd(possum, dsum);
    }

    // ---------- col sums flush
    __syncthreads();
    atomicAdd(&s_col[scol0 + tid], colsum[tid]);
    atomicAdd(&s_col[scol0 + tid + 256], colsum[tid + 256]);

    // ---------- merged finalize (last block via device-scope counter)
    __threadfence();
    __syncthreads();           // all this block's atomics fenced & issued
    if (tid == 0) lastflag = (atomicAdd(cnt, 1) == (int)gridDim.x - 1);
    __syncthreads();
    if (lastflag) {
        __threadfence();
        float ls = 0.f;        // Σ ln over s_row||s_col (contiguous 16384 floats)
        for (int j = tid; j < 16384; j += 256)
            ls += __builtin_amdgcn_logf(atomicAdd(&s_row[j], 0.f));   // coherent read
        ls *= LN2;
        int dif = 0;
        const int p0 = pid[0];
        for (int j = tid; j < 8192; j += 256) dif |= (pid[j] != p0);
        #pragma unroll
        for (int b = 1; b <= 32; b <<= 1) {
            ls  += __shfl_xor(ls, b, 64);
            dif |= __shfl_xor(dif, b, 64);
        }
        if (lane == 0) { lsw[wid] = ls; difw[wid] = dif; }
        __syncthreads();
        if (tid == 0) {
            float T = lsw[0] + lsw[1] + lsw[2] + lsw[3];
            const int F = difw[0] | difw[1] | difw[2] | difw[3];
            const float ps = atomicAdd(possum, 0.0f);
            T += 2.0f * (float)BSZ * C_OFF - 2.0f * ps;
            out[0] = F ? T / (2.0f * (float)BSZ) : 0.0f;
        }
    }
#undef STAGE
}

// ---------------------------------------------------------------- launcher
extern "C" void kernel_launch(void* const* d_in, const int* in_sizes, int n_in,
                              void* d_out, int out_size, void* d_ws, size_t ws_size,
                              hipStream_t stream)
{
    const float* za  = (const float*)d_in[0];
    const float* zt  = (const float*)d_in[1];
    const int*   pid = (const int*)d_in[2];
    float* out = (float*)d_out;

    // ws: za_bf 4MB | zt_perm 4MB | s_row[8192] s_col[8192] possum cnt
    bf16_t* za_bf   = (bf16_t*)d_ws;
    bf16_t* zt_perm = za_bf + (size_t)BSZ * DDIM;
    float*  s_row   = (float*)(zt_perm + (size_t)BSZ * DDIM);
    float*  s_col   = s_row + BSZ;
    float*  possum  = s_col + BSZ;
    int*    cnt     = (int*)(possum + 1);

    prep_kernel<<<dim3(2048), 256, 0, stream>>>(za, zt, za_bf, zt_perm, s_row);

    sim_fused<<<dim3(1024), 256, 0, stream>>>(za_bf, zt_perm, pid,
                                              s_row, s_col, possum, cnt, out);
}

// Round 11
// 128.885 us; speedup vs baseline: 2.1448x; 1.5637x over previous
//
#include <hip/hip_runtime.h>
#include <math.h>

#define BSZ    8192
#define DDIM   256
#define SCALE  33.33333333333333f   // 1/0.03
#define C_OFF  34.0f                // fixed LSE offset: |sim*SCALE| <= 33.34
#define SC_L2E 48.08983470f         // SCALE * log2(e)
#define C2     49.05163139f         // C_OFF * log2(e)

typedef __bf16 bf16_t;
typedef __bf16 bf16x8 __attribute__((ext_vector_type(8)));
typedef float  floatx4 __attribute__((ext_vector_type(4)));

__device__ __forceinline__ bf16x8 cvt8(const float* __restrict__ g)
{
    const float4 lo = *(const float4*)g;
    const float4 hi = *(const float4*)(g + 4);
    bf16x8 v;
    v[0] = (bf16_t)lo.x; v[1] = (bf16_t)lo.y; v[2] = (bf16_t)lo.z; v[3] = (bf16_t)lo.w;
    v[4] = (bf16_t)hi.x; v[5] = (bf16_t)hi.y; v[6] = (bf16_t)hi.z; v[7] = (bf16_t)hi.w;
    return v;
}

// ---------------------------------------------------------------- prep
// blocks [0,1024): za -> za_bf (row layout) + zero reduction ws (first 17 blocks)
// blocks [1024,2048): zt -> zt_perm, chunk-ordered: 8KB chunk = (colblock cb, kc);
//   slot P in chunk holds col cb*128 + (P>>2), k = kc*32 + ((P&3)^(((P>>2)>>1)&3))*8
__global__ __launch_bounds__(256) void prep_kernel(
    const float* __restrict__ za, const float* __restrict__ zt,
    bf16_t* __restrict__ za_bf, bf16_t* __restrict__ zt_perm,
    float* __restrict__ zbase)
{
    const int bid = blockIdx.x, tid = threadIdx.x;
    if (bid < 1024) {
        const int i = (bid * 256 + tid) * 8;
        *(bf16x8*)&za_bf[i] = cvt8(za + i);
        if (bid < 16) {
            const int z = bid * 1024 + tid * 4;
            *(float4*)&zbase[z] = (float4){0.f, 0.f, 0.f, 0.f};
            if (bid == 0 && tid == 0) {
                zbase[16384] = 0.f;          // total
                ((int*)zbase)[16385] = 0;    // flag
                ((int*)zbase)[16386] = 0;    // cnt
            }
        }
    } else {
        const int S     = (bid - 1024) * 256 + tid;   // global 16B-slot id
        const int chunk = S >> 9, P = S & 511;
        const int col   = P >> 2, sp = P & 3;
        const int sl    = sp ^ ((col >> 1) & 3);
        const int cb    = chunk >> 3, kc = chunk & 7;
        const float* src = zt + (size_t)(cb * 128 + col) * DDIM + kc * 32 + sl * 8;
        *(bf16x8*)(zt_perm + (size_t)S * 8) = cvt8(src);
    }
}

// ---------------------------------------------------------------- sim (R6 exact)
// Grid 64 bands x 16 strips, 4 waves. Wave w: rows [band*128+32w,+32),
// A (full K=256) resident in VGPRs from za_bf. Strip = 512 cols = 4 tiles of
// 128; B staged via fire-and-forget global_load_lds from zt_perm (1KB/issue,
// dbuf 2x8KB, 1 barrier/32-k chunk), zero bank conflicts. Fused epilogue:
// mask+exp2+row/col sums, uniform diag fixup, posv from MFMA diagonal.
// NO __threadfence / finalize merge in this kernel — R7/R8/R10 all showed the
// per-block device fence poisons the K-loop (uniform ~2x slowdown).
__global__ __launch_bounds__(256, 2) void sim_fused(
    const bf16_t* __restrict__ za_bf, const bf16_t* __restrict__ zt_perm,
    const int* __restrict__ pid,
    float* __restrict__ s_row, float* __restrict__ s_col,
    float* __restrict__ posv)
{
    __shared__ __align__(16) bf16_t Bs[2][128 * 32];   // 2 x 8 KB
    __shared__ int   pidc[512];
    __shared__ float colsum[512];

    const int bid   = blockIdx.x;
    const int strip = bid & 15, band = bid >> 4;
    const int row0  = band * 128, scol0 = strip * 512;
    const int tid   = threadIdx.x, lane = tid & 63, wid = tid >> 6;
    const int q     = lane >> 4, lc = lane & 15;
    const int rbase = row0 + wid * 32;

    pidc[tid]         = pid[scol0 + tid];
    pidc[tid + 256]   = pid[scol0 + tid + 256];
    colsum[tid]       = 0.f;
    colsum[tid + 256] = 0.f;

    // A fragments resident: af[m][kc] = A[rbase+m*16+lc][kc*32 + q*8 ..+8]
    bf16x8 af[2][8];
    #pragma unroll
    for (int m = 0; m < 2; m++) {
        const bf16_t* ga = za_bf + (size_t)(rbase + m * 16 + lc) * DDIM + q * 8;
        #pragma unroll
        for (int kc = 0; kc < 8; kc++)
            af[m][kc] = *(const bf16x8*)(ga + kc * 32);
    }

    // row pids in registers
    int prw[2][4];
    #pragma unroll
    for (int m = 0; m < 2; m++)
        #pragma unroll
        for (int r = 0; r < 4; r++)
            prw[m][r] = pid[rbase + m * 16 + q * 4 + r];

    // staging: chunk g of this strip = zt_perm bytes [(strip*32+g)*8192, +8192)
    const char* zp = (const char*)zt_perm + (size_t)(strip * 32) * 8192
                   + (wid * 64 + lane) * 16;

#define STAGE(g, b)                                                              \
    do {                                                                         \
        const char* _s = zp + (size_t)(g) * 8192;                                \
        char* _d = (char*)Bs[b] + wid * 1024;                                    \
        __builtin_amdgcn_global_load_lds(                                        \
            (const __attribute__((address_space(1))) void*)_s,                   \
            (__attribute__((address_space(3))) void*)_d, 16, 0, 0);              \
        __builtin_amdgcn_global_load_lds(                                        \
            (const __attribute__((address_space(1))) void*)(_s + 4096),          \
            (__attribute__((address_space(3))) void*)(_d + 4096), 16, 0, 0);     \
    } while (0)

    STAGE(0, 0);   // prologue

    float rowp[8] = {0.f, 0.f, 0.f, 0.f, 0.f, 0.f, 0.f, 0.f};
    const int diag_t = (row0 - scol0) >> 7;   // tile index holding the diagonal (if in [0,4))
    const int xoff   = (lc >> 1) & 3;

    for (int t = 0; t < 4; t++) {
        floatx4 acc[2][8];
        #pragma unroll
        for (int m = 0; m < 2; m++)
            #pragma unroll
            for (int n = 0; n < 8; n++)
                acc[m][n] = (floatx4){0.f, 0.f, 0.f, 0.f};

        #pragma unroll
        for (int kc = 0; kc < 8; kc++) {
            __syncthreads();                 // chunk g landed (vmcnt drain at barrier)
            const int g = t * 8 + kc;
            if (g + 1 < 32) STAGE(g + 1, (g + 1) & 1);   // fire-and-forget prefetch

            const char* B = (const char*)Bs[g & 1];
            bf16x8 bfr[8];
            #pragma unroll
            for (int n = 0; n < 8; n++)
                bfr[n] = *(const bf16x8*)(B + (n * 16 + lc) * 64 + ((q ^ xoff) * 16));

            #pragma unroll
            for (int m = 0; m < 2; m++)
                #pragma unroll
                for (int n = 0; n < 8; n++)
                    acc[m][n] = __builtin_amdgcn_mfma_f32_16x16x32_bf16(
                        af[m][kc], bfr[n], acc[m][n], 0, 0, 0);
        }

        // ---------- epilogue for tile t (next chunk's prefetch in flight)
        int pc[8];
        #pragma unroll
        for (int n = 0; n < 8; n++) pc[n] = pidc[t * 128 + n * 16 + lc];

        float colp[8] = {0.f, 0.f, 0.f, 0.f, 0.f, 0.f, 0.f, 0.f};
        #pragma unroll
        for (int m = 0; m < 2; m++) {
            #pragma unroll
            for (int r = 0; r < 4; r++) {
                const int pr = prw[m][r];
                float rsum = 0.f;
                #pragma unroll
                for (int n = 0; n < 8; n++) {
                    float e = __builtin_amdgcn_exp2f(fmaf(acc[m][n][r], SC_L2E, -C2));
                    e = (pr != pc[n]) ? e : 0.f;
                    rsum += e;
                    colp[n] += e;
                }
                rowp[m * 4 + r] += rsum;
            }
        }

        if (t == diag_t) {   // uniform branch: add back the (always same-pid) diagonal.
            // CONSTANT-INDEX select chains only — dynamic reg-array indexing
            // demotes acc[] to scratch (R5: 1.66 GB HBM writes, 3x regression).
            #pragma unroll
            for (int m = 0; m < 2; m++) {
                const int nstar = wid * 2 + m;          // runtime value, fine
                #pragma unroll
                for (int r = 0; r < 4; r++) {
                    float v = 0.f;
                    #pragma unroll
                    for (int n = 0; n < 8; n++)
                        v = (n == nstar) ? acc[m][n][r] : v;   // cndmask chain
                    float e = __builtin_amdgcn_exp2f(fmaf(v, SC_L2E, -C2));
                    const bool own = (lc == q * 4 + r);
                    e = own ? e : 0.f;
                    rowp[m * 4 + r] += e;
                    #pragma unroll
                    for (int n = 0; n < 8; n++)
                        colp[n] += (n == nstar) ? e : 0.f;     // cndmask chain
                    if (own) posv[rbase + m * 16 + q * 4 + r] = v * SCALE;
                }
            }
        }

        #pragma unroll
        for (int n = 0; n < 8; n++) {
            colp[n] += __shfl_xor(colp[n], 16, 64);
            colp[n] += __shfl_xor(colp[n], 32, 64);
        }
        if (q == 0) {
            #pragma unroll
            for (int n = 0; n < 8; n++)
                atomicAdd(&colsum[t * 128 + n * 16 + lc], colp[n]);
        }
    }

    // ---------- row sums: reduce over lc (cols), one atomic per row
    #pragma unroll
    for (int i = 0; i < 8; i++) {
        rowp[i] += __shfl_xor(rowp[i], 1, 64);
        rowp[i] += __shfl_xor(rowp[i], 2, 64);
        rowp[i] += __shfl_xor(rowp[i], 4, 64);
        rowp[i] += __shfl_xor(rowp[i], 8, 64);
    }
    float rw = rowp[0];
    #pragma unroll
    for (int idx = 1; idx < 8; idx++)
        rw = (lc == idx) ? rowp[idx] : rw;
    if (lc < 8)
        atomicAdd(&s_row[rbase + (lc >> 2) * 16 + q * 4 + (lc & 3)], rw);

    // ---------- col sums
    __syncthreads();
    atomicAdd(&s_col[scol0 + tid], colsum[tid]);
    atomicAdd(&s_col[scol0 + tid + 256], colsum[tid + 256]);
#undef STAGE
}

// ---------------------------------------------------------------- finalize (+ scalar write)
__global__ __launch_bounds__(256) void finalize_rows(
    const int* __restrict__ pid,
    const float* __restrict__ s_row, const float* __restrict__ s_col,
    const float* __restrict__ posv,
    float* __restrict__ total, int* __restrict__ flag, int* __restrict__ cnt,
    float* __restrict__ out)
{
    const int i = blockIdx.x * 256 + threadIdx.x;
    const float p = posv[i];
    const float c = (logf(s_row[i]) + C_OFF - p)
                  + (logf(s_col[i]) + C_OFF - p);

    float v = c;
    #pragma unroll
    for (int off = 32; off > 0; off >>= 1) v += __shfl_down(v, off, 64);
    if ((threadIdx.x & 63) == 0) atomicAdd(total, v);

    const unsigned long long m = __ballot(pid[i] != pid[0]);
    if (m != 0ull && (threadIdx.x & 63) == 0) atomicOr(flag, 1);

    __syncthreads();
    __threadfence();
    if (threadIdx.x == 0) {
        const int done = atomicAdd(cnt, 1);
        if (done == (int)gridDim.x - 1) {
            const float t = atomicAdd(total, 0.0f);
            const int   f = atomicOr(flag, 0);
            out[0] = f ? t / (2.0f * (float)BSZ) : 0.0f;
        }
    }
}

// ---------------------------------------------------------------- launcher
extern "C" void kernel_launch(void* const* d_in, const int* in_sizes, int n_in,
                              void* d_out, int out_size, void* d_ws, size_t ws_size,
                              hipStream_t stream)
{
    const float* za  = (const float*)d_in[0];
    const float* zt  = (const float*)d_in[1];
    const int*   pid = (const int*)d_in[2];
    float* out = (float*)d_out;

    // ws: za_bf 4MB | zt_perm 4MB | s_row[8192] s_col[8192] total flag cnt posv[8192]
    bf16_t* za_bf   = (bf16_t*)d_ws;
    bf16_t* zt_perm = za_bf + (size_t)BSZ * DDIM;
    float*  s_row   = (float*)(zt_perm + (size_t)BSZ * DDIM);
    float*  s_col   = s_row + BSZ;
    float*  total   = s_col + BSZ;
    int*    flag    = (int*)(total + 1);
    int*    cnt     = flag + 1;
    float*  posv    = (float*)(cnt + 1);

    prep_kernel<<<dim3(2048), 256, 0, stream>>>(za, zt, za_bf, zt_perm, s_row);

    sim_fused<<<dim3(1024), 256, 0, stream>>>(za_bf, zt_perm, pid,
                                              s_row, s_col, posv);

    finalize_rows<<<dim3(BSZ / 256), 256, 0, stream>>>(
        pid, s_row, s_col, posv, total, flag, cnt, out);
}